// Round 10
// baseline (597.076 us; speedup 1.0000x reference)
//
#include <hip/hip_runtime.h>
#include <hip/hip_bf16.h>
#include <stdint.h>

typedef unsigned short u16;
typedef unsigned int   u32;
typedef unsigned long long u64;
typedef __attribute__((ext_vector_type(8))) short short8;   // 8 bf16 = MFMA A/B frag
typedef __attribute__((ext_vector_type(4))) float f32x4;    // MFMA C/D frag
typedef __attribute__((ext_vector_type(2))) u32   u32x2;
typedef __attribute__((ext_vector_type(4))) u32   u32x4;

#define DEV static __device__ __forceinline__

constexpr int N_  = 10000;
constexpr int T_  = 32;
constexpr int E_  = 320000;
constexpr int E2_ = 160000;

DEV u16 f2bf(float f) {
    union { float f; u32 u; } v; v.f = f;
    u32 u = v.u;
    return (u16)((u + 0x7fffu + ((u >> 16) & 1u)) >> 16);   // RNE
}
DEV float bf2f(u16 h) {
    union { u32 u; float f; } v; v.u = ((u32)h) << 16; return v.f;
}
DEV float asf(u32 u) {
    union { u32 u; float f; } v; v.u = u; return v.f;
}
DEV u32 cvt_pk_bf16(float lo, float hi) {
    u32 r;
    asm("v_cvt_pk_bf16_f32 %0, %1, %2" : "=v"(r) : "v"(lo), "v"(hi));
    return r;
}
DEV float lrelu(float x) { return x > 0.f ? x : 0.01f * x; }

DEV float fexp2(float x) {
#if __has_builtin(__builtin_amdgcn_exp2f)
    return __builtin_amdgcn_exp2f(x);
#else
    return exp2f(x);
#endif
}
DEV float frcp(float x) {
#if __has_builtin(__builtin_amdgcn_rcpf)
    return __builtin_amdgcn_rcpf(x);
#else
    return 1.0f / x;
#endif
}
DEV float fsig(float x)  { return frcp(1.f + fexp2(-1.4426950408889634f * x)); }
DEV float ftanh_(float x){ return 1.f - 2.f * frcp(1.f + fexp2(2.8853900817779268f * x)); }

// ---------------------------------------------------------------------------
// xtab[dir][sym][512] = emb_url[sym] @ Wih.T + b   (bf16), float4 W loads
// ---------------------------------------------------------------------------
__global__ void k_xtab(const float* __restrict__ emb,
                       const float* __restrict__ WihF, const float* __restrict__ bF,
                       const float* __restrict__ WihB, const float* __restrict__ bB,
                       u16* __restrict__ xtab) {
    int sym = blockIdx.x, dir = blockIdx.y, o = threadIdx.x;   // block 512
    const float* W = dir ? WihB : WihF;
    const float* b = dir ? bB : bF;
    __shared__ float er[128];
    if (o < 128) er[o] = emb[sym * 128 + o];
    __syncthreads();
    float s = b[o];
    const float4* Wr = (const float4*)(W + (size_t)o * 128);
    for (int k4 = 0; k4 < 32; k4++) {
        float4 wv = Wr[k4];
        s += er[4*k4]   * wv.x + er[4*k4+1] * wv.y
           + er[4*k4+2] * wv.z + er[4*k4+3] * wv.w;
    }
    xtab[((size_t)(dir * 128 + sym)) * 512 + o] = f2bf(s);
}

// ---------------------------------------------------------------------------
// Merged weight transpose+convert (+K zero-padding) + misc init segment.
// ---------------------------------------------------------------------------
struct WtSeg { const float* W; u16* out; int Kd, Ks, Nw, tot; };
struct WtArgs {
    WtSeg seg[9];
    int* deg; float* bias5; const float* b0; const float* bip;
};
__global__ void k_wt_all(WtArgs a) {
    if (blockIdx.y == 9) {
        int gid = blockIdx.x * 256 + threadIdx.x;
        if (gid < N_) a.deg[gid] = 0;
        int b = gid - 10240;
        if (b >= 0 && b < 640) a.bias5[b] = (b < 512) ? a.b0[b] : a.bip[b - 512];
        return;
    }
    WtSeg sg = a.seg[blockIdx.y];
    int i = blockIdx.x * 256 + threadIdx.x;
    if (i >= sg.tot) return;
    int k = i % sg.Kd, n = (i / sg.Kd) % sg.Nw, s = i / (sg.Kd * sg.Nw);
    float v = (k < sg.Ks) ? sg.W[((size_t)s * sg.Ks + k) * sg.Nw + n] : 0.f;
    sg.out[i] = f2bf(v);
}

// ---------------------------------------------------------------------------
// Bi-LSTM: block = 512 threads (8 waves) x 16 sequences, one direction.
// Wave w owns hidden units [16w,16w+16) for all 4 gates (64 VGPR of Whh).
// h in LDS fragment-major, double-buffered; raw lgkmcnt-only barrier;
// xtab folded into MFMA C-init, prefetched one step ahead.
// This round: fast path uses shared-reciprocal gate fusion
//   i*g = (eg-1)*rcp((1+ei)(eg+1)),  h = (ec-1)*rcp((1+eo)(ec+1))
// (8 trans/r instead of 10) and s_setprio(1) around the MFMA cluster.
// ---------------------------------------------------------------------------
__global__ __launch_bounds__(512, 2) void k_lstm(
    const u16* __restrict__ xtab,      // [2][128][512] bf16 (bias folded)
    const int* __restrict__ syms,      // [N][32]
    const int* __restrict__ smask,     // [N][32]
    const float* __restrict__ WhhF,    // [512][128]
    const float* __restrict__ WhhB,
    u16* __restrict__ hcat)            // [N][256] bf16 (fwd | bwd)
{
    __shared__ u16 h_buf0[2048];       // [16 slabs][16 seq][8 elems]
    __shared__ u16 h_buf1[2048];
    __shared__ int sym_l[512];         // [t][seq]
    __shared__ int msk_l[512];         // [t][seq]
    __shared__ int anymask;

    int tid = threadIdx.x;
    int w = tid >> 6, l = tid & 63, l15 = l & 15, lg = l >> 4;
    int dir = blockIdx.y;
    int n0 = blockIdx.x * 16;
    const float* Whh = dir ? WhhB : WhhF;

    if (tid == 0) anymask = 0;
    int m0 = 0;
    for (int i = tid; i < 512; i += 512) {
        int seq = i >> 5, t = i & 31;
        int mv = smask[(size_t)n0 * 32 + i];
        sym_l[t * 16 + seq] = syms[(size_t)n0 * 32 + i];
        msk_l[t * 16 + seq] = mv;
        m0 |= (mv == 0);
    }
    for (int i = tid; i < 2048; i += 512) h_buf0[i] = 0;
    if (__ballot(m0) != 0ull && l == 0) anymask = 1;

    // A fragments: wave w covers gate gg, units 128*gg + 16*w + row
    short8 aw[4][4];
#pragma unroll
    for (int gg = 0; gg < 4; gg++)
#pragma unroll
    for (int kk = 0; kk < 4; kk++) {
        const float* p = Whh + (size_t)(128 * gg + 16 * w + l15) * 128 + 32 * kk + 8 * lg;
        const float4* pp = (const float4*)p;
        float4 x0 = pp[0], x1 = pp[1];
        short8 v;
        v[0] = (short)f2bf(x0.x); v[1] = (short)f2bf(x0.y);
        v[2] = (short)f2bf(x0.z); v[3] = (short)f2bf(x0.w);
        v[4] = (short)f2bf(x1.x); v[5] = (short)f2bf(x1.y);
        v[6] = (short)f2bf(x1.z); v[7] = (short)f2bf(x1.w);
        aw[gg][kk] = v;
    }

    float hreg[4] = {0, 0, 0, 0};
    float creg[4] = {0, 0, 0, 0};
    int jb = 16 * w + 4 * lg;          // hidden-unit base for this lane
    int wsk = 2 * w + (lg >> 1);       // write slab index (= jb>>3)
    int wof = (wsk * 16 + l15) * 8 + 4 * (lg & 1);
    const u16* xbase = xtab + (size_t)dir * 128 * 512 + jb;
    __syncthreads();
    bool masked = anymask != 0;

    u32x2 xt[4];
    {   // prologue: prefetch xtab gate inputs for step 0
        int t0 = dir ? 31 : 0;
        int sym0 = sym_l[t0 * 16 + l15];
        const u16* xr = xbase + (size_t)sym0 * 512;
#pragma unroll
        for (int gg = 0; gg < 4; gg++) xt[gg] = *(const u32x2*)(xr + gg * 128);
    }

    constexpr float C1 = 1.4426950408889634f;   // log2(e)
    constexpr float C2 = 2.8853900817779268f;   // 2*log2(e)

    auto step = [&](int st, const u16* rb, u16* wb, bool wr, bool usemask) {
        int t = dir ? (31 - st) : st;

        // B fragments: contiguous 1KB slab per wave, conflict-free
        short8 bh[4];
#pragma unroll
        for (int kk = 0; kk < 4; kk++)
            bh[kk] = *(const short8*)&rb[((kk * 4 + lg) * 16 + l15) * 8];

        __builtin_amdgcn_s_setprio(1);
        f32x4 acc[4];
#pragma unroll
        for (int gg = 0; gg < 4; gg++) {
            // init C with the xtab gate inputs (x@Wih.T + b)
            f32x4 a = { asf(xt[gg][0] << 16), asf(xt[gg][0] & 0xffff0000u),
                        asf(xt[gg][1] << 16), asf(xt[gg][1] & 0xffff0000u) };
#pragma unroll
            for (int kk = 0; kk < 4; kk++)
                a = __builtin_amdgcn_mfma_f32_16x16x32_bf16(aw[gg][kk], bh[kk], a, 0, 0, 0);
            acc[gg] = a;
        }
        __builtin_amdgcn_s_setprio(0);

        // prefetch next step's xtab inputs into the SAME regs; the raw
        // barrier below does NOT drain vmcnt -> latency spans the barrier.
        if (wr) {
            int stn = st + 1;
            int tn = dir ? (31 - stn) : stn;
            int symn = sym_l[tn * 16 + l15];
            const u16* xr = xbase + (size_t)symn * 512;
#pragma unroll
            for (int gg = 0; gg < 4; gg++) xt[gg] = *(const u32x2*)(xr + gg * 128);
        }

        if (usemask) {
            int mt_i = msk_l[t * 16 + l15];
            bool mb = mt_i != 0;
#pragma unroll
            for (int r = 0; r < 4; r++) {
                float i_ = fsig(acc[0][r]), f_ = fsig(acc[1][r]);
                float g_ = ftanh_(acc[2][r]), o_ = fsig(acc[3][r]);
                float cn = f_ * creg[r] + i_ * g_;
                float hn = o_ * ftanh_(cn);
                hreg[r] = mb ? hn : hreg[r];
                creg[r] = mb ? cn : creg[r];
            }
        } else {
            // fused-reciprocal gate math: 5 exp + 3 rcp per r (was 5+5)
#pragma unroll
            for (int r = 0; r < 4; r++) {
                float ei = fexp2(-C1 * acc[0][r]);
                float ef = fexp2(-C1 * acc[1][r]);
                float eg = fexp2( C2 * acc[2][r]);
                float eo = fexp2(-C1 * acc[3][r]);
                float f_ = frcp(1.f + ef);
                // i*g = (eg-1) / ((1+ei)(eg+1))
                float ig = (eg - 1.f) * frcp((1.f + ei) * (eg + 1.f));
                float cn = f_ * creg[r] + ig;
                float ec = fexp2(C2 * cn);
                // h = o * tanh(cn) = (ec-1) / ((1+eo)(ec+1))
                hreg[r] = (ec - 1.f) * frcp((1.f + eo) * (ec + 1.f));
                creg[r] = cn;
            }
        }
        if (wr) {
            u32x2 pk;
            pk[0] = cvt_pk_bf16(hreg[0], hreg[1]);
            pk[1] = cvt_pk_bf16(hreg[2], hreg[3]);
            *(u32x2*)&wb[wof] = pk;
            // raw barrier: wait LDS ops only, NOT vmcnt
            asm volatile("s_waitcnt lgkmcnt(0)" ::: "memory");
            __builtin_amdgcn_s_barrier();
        }
    };

    if (masked) {
        for (int st2 = 0; st2 < 15; st2++) {
            step(2 * st2,     h_buf0, h_buf1, true, true);
            step(2 * st2 + 1, h_buf1, h_buf0, true, true);
        }
        step(30, h_buf0, h_buf1, true, true);
        step(31, h_buf1, h_buf0, false, true);
    } else {
        for (int st2 = 0; st2 < 15; st2++) {
            step(2 * st2,     h_buf0, h_buf1, true, false);
            step(2 * st2 + 1, h_buf1, h_buf0, true, false);
        }
        step(30, h_buf0, h_buf1, true, false);
        step(31, h_buf1, h_buf0, false, false);
    }

    // final hidden -> hcat[n][dir*128 + j]
    {
        u32x2 pk;
        pk[0] = cvt_pk_bf16(hreg[0], hreg[1]);
        pk[1] = cvt_pk_bf16(hreg[2], hreg[3]);
        *(u32x2*)&hcat[(size_t)(n0 + l15) * 256 + dir * 128 + jb] = pk;
    }
}

// ---------------------------------------------------------------------------
// Generic MFMA GEMM: C[M,128] = act(A1@B1 [+ A2@B2] + bias), bf16 in/out.
// ---------------------------------------------------------------------------
template<int ACT, int DUAL>
__global__ __launch_bounds__(256) void k_gemm(
    const u16* __restrict__ A1, int lda1, int soA1,
    const u16* __restrict__ A2, int lda2, int soA2,
    const u16* __restrict__ B1, int soB1,
    const u16* __restrict__ B2, int soB2,
    const float* __restrict__ bias, int soBias,
    u16* __restrict__ C, int ldc, int soC, int M, int K)
{
    int s = blockIdx.y;
    A1 += (size_t)s * soA1;
    if (DUAL) A2 += (size_t)s * soA2;
    B1 += (size_t)s * soB1;
    if (DUAL) B2 += (size_t)s * soB2;
    if (bias) bias += (size_t)s * soBias;
    C += (size_t)s * soC;

    int tid = threadIdx.x;
    int w = tid >> 6, l = tid & 63, l15 = l & 15, lg = l >> 4;
    int mbase = blockIdx.x * 64 + w * 16;
    int arow = mbase + l15; if (arow >= M) arow = M - 1;

    f32x4 acc[8];
#pragma unroll
    for (int nt = 0; nt < 8; nt++) {
        float bv = bias ? bias[16 * nt + l15] : 0.f;
        acc[nt] = (f32x4){bv, bv, bv, bv};
    }
    for (int k0 = 0; k0 < K; k0 += 32) {
        int k = k0 + 8 * lg;
        short8 a1 = *(const short8*)&A1[(size_t)arow * lda1 + k];
        short8 a2;
        if (DUAL) a2 = *(const short8*)&A2[(size_t)arow * lda2 + k];
#pragma unroll
        for (int nt = 0; nt < 8; nt++) {
            short8 b1 = *(const short8*)&B1[(size_t)(16 * nt + l15) * K + k];
            acc[nt] = __builtin_amdgcn_mfma_f32_16x16x32_bf16(a1, b1, acc[nt], 0, 0, 0);
            if (DUAL) {
                short8 b2 = *(const short8*)&B2[(size_t)(16 * nt + l15) * K + k];
                acc[nt] = __builtin_amdgcn_mfma_f32_16x16x32_bf16(a2, b2, acc[nt], 0, 0, 0);
            }
        }
    }
#pragma unroll
    for (int nt = 0; nt < 8; nt++)
#pragma unroll
    for (int r = 0; r < 4; r++) {
        int m = mbase + 4 * lg + r;
        if (m < M) {
            float v = acc[nt][r];
            if (ACT == 1) v = lrelu(v);
            C[(size_t)m * ldc + 16 * nt + l15] = f2bf(v);
        }
    }
}

// ---------------------------------------------------------------------------
// Fused: y==0 -> vec_url GEMM (F0 cols 0..127, pitch 640);
//        y==1 -> embedding/ip pack (F0 cols 128..543).
// F0 cols 544..639 are never written: they feed only the zero-padded K>=32
// weights of the ip stream (poison bf16 is a finite denormal -> inert).
// ---------------------------------------------------------------------------
__global__ __launch_bounds__(256) void k_fcpack(
    const u16* __restrict__ hcat, const u16* __restrict__ Bt,   // [128][256]
    const float* __restrict__ bias, u16* __restrict__ F0,
    const int* __restrict__ ic, const int* __restrict__ ico,
    const int* __restrict__ isl, const float* __restrict__ ip,
    const float* __restrict__ ecat, const float* __restrict__ ecou,
    const float* __restrict__ esl, int M)
{
    if (blockIdx.y == 1) {
        int gid = blockIdx.x * 256 + threadIdx.x;   // 157*256 = 40192 threads
        const int TOT = N_ * 416;
        for (int i = gid; i < TOT; i += 40192) {
            int n = i / 416, c = i - n * 416;
            float v;
            if (c < 128)      v = ecat[(size_t)ic[n]  * 128 + c];
            else if (c < 256) v = ecou[(size_t)ico[n] * 128 + (c - 128)];
            else if (c < 384) v = esl [(size_t)isl[n] * 128 + (c - 256)];
            else              v = ip  [(size_t)n * 32 + (c - 384)];
            F0[(size_t)n * 640 + 128 + c] = f2bf(v);
        }
        return;
    }
    int tid = threadIdx.x;
    int w = tid >> 6, l = tid & 63, l15 = l & 15, lg = l >> 4;
    int mbase = blockIdx.x * 64 + w * 16;
    int arow = mbase + l15; if (arow >= M) arow = M - 1;

    f32x4 acc[8];
#pragma unroll
    for (int nt = 0; nt < 8; nt++) {
        float bv = bias[16 * nt + l15];
        acc[nt] = (f32x4){bv, bv, bv, bv};
    }
    for (int k0 = 0; k0 < 256; k0 += 32) {
        int k = k0 + 8 * lg;
        short8 a1 = *(const short8*)&hcat[(size_t)arow * 256 + k];
#pragma unroll
        for (int nt = 0; nt < 8; nt++) {
            short8 b1 = *(const short8*)&Bt[(size_t)(16 * nt + l15) * 256 + k];
            acc[nt] = __builtin_amdgcn_mfma_f32_16x16x32_bf16(a1, b1, acc[nt], 0, 0, 0);
        }
    }
#pragma unroll
    for (int nt = 0; nt < 8; nt++)
#pragma unroll
    for (int r = 0; r < 4; r++) {
        int m = mbase + 4 * lg + r;
        if (m < M)
            F0[(size_t)m * 640 + 16 * nt + l15] = f2bf(lrelu(acc[nt][r]));
    }
}

// ---------------------------------------------------------------------------
// CSR build
// ---------------------------------------------------------------------------
__global__ void k_hist(const int* __restrict__ dst, int E, int* __restrict__ deg) {
    int e = blockIdx.x * 256 + threadIdx.x;
    if (e < E) atomicAdd(&deg[dst[e]], 1);
}
__global__ void k_scan(const int* __restrict__ deg, int* __restrict__ rowptr,
                       int* __restrict__ cursor, int n) {
    __shared__ int part[1024];
    int tid = threadIdx.x;
    const int CH = 10;
    int base = tid * CH;
    int s = 0;
#pragma unroll
    for (int i = 0; i < CH; i++) { int idx = base + i; if (idx < n) s += deg[idx]; }
    part[tid] = s; __syncthreads();
    for (int off = 1; off < 1024; off <<= 1) {
        int v = (tid >= off) ? part[tid - off] : 0;
        __syncthreads();
        part[tid] += v;
        __syncthreads();
    }
    int run = part[tid] - s;
    for (int i = 0; i < CH; i++) {
        int idx = base + i;
        if (idx < n) { rowptr[idx] = run; cursor[idx] = run; run += deg[idx]; }
    }
    if (tid == 1023) rowptr[n] = part[1023];
}
__global__ void k_fill(const int* __restrict__ src, const int* __restrict__ dst, int E,
                       int* __restrict__ cursor, int* __restrict__ colsrc) {
    int e = blockIdx.x * 256 + threadIdx.x;
    if (e < E) {
        int pos = atomicAdd(&cursor[dst[e]], 1);
        colsrc[pos] = src[e];
    }
}

// ---------------------------------------------------------------------------
// Mean aggregation: column-chunked. Row pitch 640 u16 = 320 u32 = 5 chunks
// of 64 u32. Grid (N/4, 5); per-chunk table 2.56 MB < 4 MB L2/XCD.
// ---------------------------------------------------------------------------
__global__ __launch_bounds__(256) void k_agg(const u16* __restrict__ F,
                                             const int* __restrict__ rowptr,
                                             const int* __restrict__ colsrc,
                                             u16* __restrict__ out, int N) {
    int w = threadIdx.x >> 6, l = threadIdx.x & 63;
    int n = blockIdx.x * 4 + w;
    if (n >= N) return;
    int cu = blockIdx.y * 64 + l;          // u32 column in [0,320)
    const u32* Fc = (const u32*)F;         // row pitch 320 u32
    int beg = rowptr[n], end = rowptr[n + 1];
    float a0 = 0.f, a1 = 0.f;

    int e = beg;
    for (; e + 8 <= end; e += 8) {
        int s[8];
#pragma unroll
        for (int j = 0; j < 8; j++) s[j] = colsrc[e + j];
        u32 v[8];
#pragma unroll
        for (int j = 0; j < 8; j++) v[j] = Fc[(size_t)s[j] * 320 + cu];
#pragma unroll
        for (int j = 0; j < 8; j++) {
            a0 += asf(v[j] << 16);
            a1 += asf(v[j] & 0xffff0000u);
        }
    }
    for (; e < end; e++) {
        u32 v = Fc[(size_t)colsrc[e] * 320 + cu];
        a0 += asf(v << 16);
        a1 += asf(v & 0xffff0000u);
    }

    int dg = end - beg; if (dg < 1) dg = 1;
    float inv = 1.f / (float)dg;
    ((u32*)out)[(size_t)n * 320 + cu] = cvt_pk_bf16(a0 * inv, a1 * inv);
}

// ---------------------------------------------------------------------------
// Fused attnlin-GEMM + attention: block = 5 waves = 80 rows = 16 nodes.
// ---------------------------------------------------------------------------
__global__ __launch_bounds__(320) void k_zattn(
    const u16* __restrict__ H1,        // rows r=(n*5+s) at H1 + r*128
    const u16* __restrict__ Bt,        // wt_attn [128][128]
    const float* __restrict__ attnW,   // [128]
    float* __restrict__ aOut,          // [N][5]
    u16* __restrict__ hT)              // [N][128]
{
    constexpr int ZP = 136;            // u16 pitch (272 B, 16B-aligned rows)
    __shared__ u16 zl[80 * ZP];
    int tid = threadIdx.x;
    int w = tid >> 6, l = tid & 63, l15 = l & 15, lg = l >> 4;
    int rbase = blockIdx.x * 80 + w * 16;

    f32x4 acc[8];
#pragma unroll
    for (int nt = 0; nt < 8; nt++) acc[nt] = (f32x4){0.f, 0.f, 0.f, 0.f};
    for (int k0 = 0; k0 < 128; k0 += 32) {
        int k = k0 + 8 * lg;
        short8 a1 = *(const short8*)&H1[(size_t)(rbase + l15) * 128 + k];
#pragma unroll
        for (int nt = 0; nt < 8; nt++) {
            short8 b1 = *(const short8*)&Bt[(size_t)(16 * nt + l15) * 128 + k];
            acc[nt] = __builtin_amdgcn_mfma_f32_16x16x32_bf16(a1, b1, acc[nt], 0, 0, 0);
        }
    }
#pragma unroll
    for (int nt = 0; nt < 8; nt++)
#pragma unroll
    for (int r = 0; r < 4; r++)
        zl[(w * 16 + 4 * lg + r) * ZP + 16 * nt + l15] = f2bf(acc[nt][r]);
    __syncthreads();

    if (tid < 256) {
        int node = tid >> 4;           // 0..15
        int j = tid & 15;
        int d0 = j * 8;
        float4 wa0 = *(const float4*)(attnW + d0);
        float4 wa1 = *(const float4*)(attnW + d0 + 4);
        float z[5][8], lgt[5];
#pragma unroll
        for (int s = 0; s < 5; s++) {
            const u16* zr = &zl[(node * 5 + s) * ZP + d0];
            u32x4 v = *(const u32x4*)zr;
#pragma unroll
            for (int q = 0; q < 4; q++) {
                z[s][2*q]   = asf(v[q] << 16);
                z[s][2*q+1] = asf(v[q] & 0xffff0000u);
            }
            float p = z[s][0]*wa0.x + z[s][1]*wa0.y + z[s][2]*wa0.z + z[s][3]*wa0.w
                    + z[s][4]*wa1.x + z[s][5]*wa1.y + z[s][6]*wa1.z + z[s][7]*wa1.w;
#pragma unroll
            for (int m = 1; m < 16; m <<= 1) p += __shfl_xor(p, m, 64);
            lgt[s] = p;
        }
        float mx = lgt[0];
#pragma unroll
        for (int s = 1; s < 5; s++) mx = fmaxf(mx, lgt[s]);
        float ex[5], sum = 0.f;
#pragma unroll
        for (int s = 0; s < 5; s++) { ex[s] = __expf(lgt[s] - mx); sum += ex[s]; }
        float inv = 1.f / sum;
        float a[5];
#pragma unroll
        for (int s = 0; s < 5; s++) a[s] = ex[s] * inv;
        float h[8] = {0,0,0,0,0,0,0,0};
#pragma unroll
        for (int s = 0; s < 5; s++)
#pragma unroll
            for (int q = 0; q < 8; q++) h[q] += a[s] * z[s][q];
        int gn = blockIdx.x * 16 + node;
        u32x4 o;
#pragma unroll
        for (int q = 0; q < 4; q++) o[q] = cvt_pk_bf16(h[2*q], h[2*q+1]);
        *(u32x4*)&hT[(size_t)gn * 128 + d0] = o;
        if (j == 0) {
#pragma unroll
            for (int s = 0; s < 5; s++) aOut[(size_t)gn * 5 + s] = a[s];
        }
    }
}

// ---------------------------------------------------------------------------
// Edge MLP fused: score + attn_e outputs.
// ---------------------------------------------------------------------------
__global__ __launch_bounds__(256) void k_edge(const u16* __restrict__ hT,
                                              const int* __restrict__ esrc,
                                              const int* __restrict__ edst,
                                              const u16* __restrict__ fcWt,  // [128][256]
                                              const float* __restrict__ fcb,
                                              const float* __restrict__ fcoW, // [128][2]
                                              const float* __restrict__ fcob,
                                              const float* __restrict__ aA,   // [N][5]
                                              float* __restrict__ score,      // [E2][2]
                                              float* __restrict__ attne,      // [E2][2][5]
                                              int E2) {
    int tid = threadIdx.x;
    int w = tid >> 6, l = tid & 63, l15 = l & 15, lg = l >> 4;
    int eb = (blockIdx.x * 4 + w) * 16;
    int arow = eb + l15; if (arow >= E2) arow = E2 - 1;
    int sn = esrc[arow], dn = edst[arow];

    f32x4 acc[8];
#pragma unroll
    for (int nt = 0; nt < 8; nt++) {
        float bv = fcb[16 * nt + l15];
        acc[nt] = (f32x4){bv, bv, bv, bv};
    }
#pragma unroll
    for (int kk = 0; kk < 8; kk++) {
        int k = 32 * kk + 8 * lg;
        const u16* ap = (k < 128) ? &hT[(size_t)sn * 128 + k]
                                  : &hT[(size_t)dn * 128 + (k - 128)];
        short8 a = *(const short8*)ap;
#pragma unroll
        for (int nt = 0; nt < 8; nt++) {
            short8 b = *(const short8*)&fcWt[(size_t)(16 * nt + l15) * 256 + k];
            acc[nt] = __builtin_amdgcn_mfma_f32_16x16x32_bf16(a, b, acc[nt], 0, 0, 0);
        }
    }
    float p0[4] = {0,0,0,0}, p1[4] = {0,0,0,0};
#pragma unroll
    for (int nt = 0; nt < 8; nt++) {
        int c = 16 * nt + l15;
        float w0 = fcoW[c * 2], w1 = fcoW[c * 2 + 1];
#pragma unroll
        for (int r = 0; r < 4; r++) {
            float hd = lrelu(acc[nt][r]);
            p0[r] += hd * w0; p1[r] += hd * w1;
        }
    }
#pragma unroll
    for (int m = 1; m < 16; m <<= 1) {
#pragma unroll
        for (int r = 0; r < 4; r++) {
            p0[r] += __shfl_xor(p0[r], m, 64);
            p1[r] += __shfl_xor(p1[r], m, 64);
        }
    }
    if (l15 == 0) {
        float b0v = fcob[0], b1v = fcob[1];
#pragma unroll
        for (int r = 0; r < 4; r++) {
            int e = eb + 4 * lg + r;
            if (e < E2) {
                score[(size_t)e * 2 + 0] = p0[r] + b0v;
                score[(size_t)e * 2 + 1] = p1[r] + b1v;
            }
        }
    }
    // fused attn_e: wave covers 16 edges x 10 floats, coalesced writes
#pragma unroll
    for (int pass = 0; pass < 3; pass++) {
        int idx = pass * 64 + l;
        if (idx < 160) {
            int e = eb + idx / 10;
            int j = idx % 10;
            int s = esrc[e];
            attne[(size_t)e * 10 + j] = aA[(size_t)s * 5 + (j >= 5 ? j - 5 : j)];
        }
    }
}

// ---------------------------------------------------------------------------
extern "C" void kernel_launch(void* const* d_in, const int* in_sizes, int n_in,
                              void* d_out, int out_size, void* d_ws, size_t ws_size,
                              hipStream_t stream) {
    const int* inp_s   = (const int*)d_in[0];
    const int* inp_sm  = (const int*)d_in[1];
    const int* inp_c   = (const int*)d_in[2];
    const int* inp_co  = (const int*)d_in[3];
    const int* inp_sl  = (const int*)d_in[4];
    const float* inp_ip = (const float*)d_in[5];
    const int* blk_src = (const int*)d_in[6];
    const int* blk_dst = (const int*)d_in[7];
    const int* e_src   = (const int*)d_in[8];
    const int* e_dst   = (const int*)d_in[9];
    const float* emb_url = (const float*)d_in[10];
    const float* emb_cat = (const float*)d_in[11];
    const float* emb_cou = (const float*)d_in[12];
    const float* emb_sl  = (const float*)d_in[13];
    const float* Wih_f = (const float*)d_in[14];
    const float* Whh_f = (const float*)d_in[15];
    const float* b_f   = (const float*)d_in[16];
    const float* Wih_b = (const float*)d_in[17];
    const float* Whh_b = (const float*)d_in[18];
    const float* b_b   = (const float*)d_in[19];
    const float* fc_lstm_W = (const float*)d_in[20];
    const float* fc_lstm_b = (const float*)d_in[21];
    const float* attnlin_W = (const float*)d_in[22];
    const float* attn_W    = (const float*)d_in[23];
    /* d_in[24] attn_b: softmax shift-invariant, unused */
    const float* W0_self  = (const float*)d_in[25];
    const float* W0_neigh = (const float*)d_in[26];
    const float* b0       = (const float*)d_in[27];
    const float* Wip_self  = (const float*)d_in[28];
    const float* Wip_neigh = (const float*)d_in[29];
    const float* bip       = (const float*)d_in[30];
    const float* W1_self  = (const float*)d_in[31];
    const float* W1_neigh = (const float*)d_in[32];
    const float* b1       = (const float*)d_in[33];
    const float* fc_W  = (const float*)d_in[34];
    const float* fc_b  = (const float*)d_in[35];
    const float* fco_W = (const float*)d_in[36];
    const float* fco_b = (const float*)d_in[37];

    char* ws = (char*)d_ws;
    size_t off = 0;
    auto alloc = [&](size_t bytes) -> char* {
        char* p = ws + off;
        off += (bytes + 255) & ~(size_t)255;
        return p;
    };
    u16* xtab      = (u16*)alloc((size_t)2 * 128 * 512 * 2);
    u16* hcat      = (u16*)alloc((size_t)N_ * 256 * 2);
    u16* wt_fclstm = (u16*)alloc((size_t)128 * 256 * 2);
    u16* wt_w05s   = (u16*)alloc((size_t)5 * 128 * 128 * 2);  // 4 emb + padded ip
    u16* wt_w05n   = (u16*)alloc((size_t)5 * 128 * 128 * 2);
    u16* wt_w1s    = (u16*)alloc((size_t)5 * 128 * 128 * 2);
    u16* wt_w1n    = (u16*)alloc((size_t)5 * 128 * 128 * 2);
    u16* wt_attn   = (u16*)alloc((size_t)128 * 128 * 2);
    u16* wt_fc     = (u16*)alloc((size_t)128 * 256 * 2);
    float* bias5   = (float*)alloc((size_t)5 * 128 * 4);
    u16* F0        = (u16*)alloc((size_t)N_ * 640 * 2);       // pitch 640 (chunked agg)
    u16* NEI       = (u16*)alloc((size_t)N_ * 640 * 2);
    u16* F1        = (u16*)alloc((size_t)N_ * 640 * 2);
    u16* H1        = (u16*)alloc((size_t)N_ * 640 * 2);
    u16* hT        = (u16*)alloc((size_t)N_ * 128 * 2);
    float* aA      = (float*)alloc((size_t)N_ * 5 * 4);
    int* deg       = (int*)alloc((size_t)N_ * 4);
    int* rowptr    = (int*)alloc((size_t)(N_ + 1) * 4);
    int* cursor    = (int*)alloc((size_t)N_ * 4);
    int* colsrc    = (int*)alloc((size_t)E_ * 4);
    (void)ws_size; (void)in_sizes; (void)n_in; (void)out_size;

    float* out_score = (float*)d_out;
    float* out_attne = out_score + (size_t)2 * E2_;

    // --- LSTM prep + weight prep (+deg zero, bias5 build) ---
    k_xtab<<<dim3(128, 2), dim3(512), 0, stream>>>(emb_url, Wih_f, b_f, Wih_b, b_b, xtab);
    {
        WtArgs a;
        a.seg[0] = {fc_lstm_W, wt_fclstm,            256, 256, 128, 1 * 128 * 256};
        a.seg[1] = {W0_self,   wt_w05s,              128, 128, 128, 4 * 128 * 128};
        a.seg[2] = {W0_neigh,  wt_w05n,              128, 128, 128, 4 * 128 * 128};
        a.seg[3] = {Wip_self,  wt_w05s + 4 * 16384,  128,  32, 128, 1 * 128 * 128};
        a.seg[4] = {Wip_neigh, wt_w05n + 4 * 16384,  128,  32, 128, 1 * 128 * 128};
        a.seg[5] = {W1_self,   wt_w1s,               128, 128, 128, 5 * 128 * 128};
        a.seg[6] = {W1_neigh,  wt_w1n,               128, 128, 128, 5 * 128 * 128};
        a.seg[7] = {attnlin_W, wt_attn,              128, 128, 128, 1 * 128 * 128};
        a.seg[8] = {fc_W,      wt_fc,                256, 256, 128, 1 * 128 * 256};
        a.deg = deg; a.bias5 = bias5; a.b0 = b0; a.bip = bip;
        k_wt_all<<<dim3((5 * 128 * 128 + 255) / 256, 10), dim3(256), 0, stream>>>(a);
    }

    // --- CSR build ---
    k_hist<<<dim3((E_ + 255) / 256), dim3(256), 0, stream>>>(blk_dst, E_, deg);
    k_scan<<<dim3(1), dim3(1024), 0, stream>>>(deg, rowptr, cursor, N_);
    k_fill<<<dim3((E_ + 255) / 256), dim3(256), 0, stream>>>(blk_src, blk_dst, E_, cursor, colsrc);

    k_lstm<<<dim3(N_ / 16, 2), dim3(512), 0, stream>>>(xtab, inp_s, inp_sm, Whh_f, Whh_b, hcat);

    // vec_url GEMM + feature pack in one dispatch (F0 pitch 640)
    k_fcpack<<<dim3((N_ + 63) / 64, 2), dim3(256), 0, stream>>>(
        hcat, wt_fclstm, fc_lstm_b, F0,
        inp_c, inp_co, inp_sl, inp_ip, emb_cat, emb_cou, emb_sl, N_);

    // --- SAGE layer 0: chunked agg + 5-stream dual GEMM ---
    k_agg<<<dim3((N_ + 3) / 4, 5), dim3(256), 0, stream>>>(F0, rowptr, colsrc, NEI, N_);
    k_gemm<1, 1><<<dim3((N_ + 63) / 64, 5), dim3(256), 0, stream>>>(
        F0, 640, 128, NEI, 640, 128, wt_w05s, 128 * 128, wt_w05n, 128 * 128,
        bias5, 128, F1, 640, 128, N_, 128);

    // --- SAGE layer 1 ---
    k_agg<<<dim3((N_ + 3) / 4, 5), dim3(256), 0, stream>>>(F1, rowptr, colsrc, NEI, N_);
    k_gemm<1, 1><<<dim3((N_ + 63) / 64, 5), dim3(256), 0, stream>>>(
        F1, 640, 128, NEI, 640, 128, wt_w1s, 128 * 128, wt_w1n, 128 * 128,
        b1, 128, H1, 640, 128, N_, 128);

    // --- fused attention (GEMM + softmax + fuse) ---
    k_zattn<<<dim3(N_ / 16), dim3(320), 0, stream>>>(H1, wt_attn, attn_W, aA, hT);

    // --- edge scoring (attn_e fused in) ---
    k_edge<<<dim3(E2_ / 64), dim3(256), 0, stream>>>(hT, e_src, e_dst, wt_fc, fc_b,
                                                     fco_W, fco_b, aA,
                                                     out_score, out_attne, E2_);
}

// Round 11
// 572.262 us; speedup vs baseline: 1.0434x; 1.0434x over previous
//
#include <hip/hip_runtime.h>
#include <hip/hip_bf16.h>
#include <stdint.h>

typedef unsigned short u16;
typedef unsigned int   u32;
typedef unsigned long long u64;
typedef __attribute__((ext_vector_type(8))) short short8;   // 8 bf16 = MFMA A/B frag
typedef __attribute__((ext_vector_type(4))) float f32x4;    // MFMA C/D frag
typedef __attribute__((ext_vector_type(2))) u32   u32x2;
typedef __attribute__((ext_vector_type(4))) u32   u32x4;

#define DEV static __device__ __forceinline__

constexpr int N_  = 10000;
constexpr int T_  = 32;
constexpr int E_  = 320000;
constexpr int E2_ = 160000;

DEV u16 f2bf(float f) {
    union { float f; u32 u; } v; v.f = f;
    u32 u = v.u;
    return (u16)((u + 0x7fffu + ((u >> 16) & 1u)) >> 16);   // RNE
}
DEV float bf2f(u16 h) {
    union { u32 u; float f; } v; v.u = ((u32)h) << 16; return v.f;
}
DEV float asf(u32 u) {
    union { u32 u; float f; } v; v.u = u; return v.f;
}
DEV u32 cvt_pk_bf16(float lo, float hi) {
    u32 r;
    asm("v_cvt_pk_bf16_f32 %0, %1, %2" : "=v"(r) : "v"(lo), "v"(hi));
    return r;
}
DEV float lrelu(float x) { return x > 0.f ? x : 0.01f * x; }

DEV float fexp2(float x) {
#if __has_builtin(__builtin_amdgcn_exp2f)
    return __builtin_amdgcn_exp2f(x);
#else
    return exp2f(x);
#endif
}
DEV float frcp(float x) {
#if __has_builtin(__builtin_amdgcn_rcpf)
    return __builtin_amdgcn_rcpf(x);
#else
    return 1.0f / x;
#endif
}
DEV float fsig(float x)  { return frcp(1.f + fexp2(-1.4426950408889634f * x)); }
DEV float ftanh_(float x){ return 1.f - 2.f * frcp(1.f + fexp2(2.8853900817779268f * x)); }

// ---------------------------------------------------------------------------
// xtab[dir][sym][512] = emb_url[sym] @ Wih.T + b   (bf16), float4 W loads
// ---------------------------------------------------------------------------
__global__ void k_xtab(const float* __restrict__ emb,
                       const float* __restrict__ WihF, const float* __restrict__ bF,
                       const float* __restrict__ WihB, const float* __restrict__ bB,
                       u16* __restrict__ xtab) {
    int sym = blockIdx.x, dir = blockIdx.y, o = threadIdx.x;   // block 512
    const float* W = dir ? WihB : WihF;
    const float* b = dir ? bB : bF;
    __shared__ float er[128];
    if (o < 128) er[o] = emb[sym * 128 + o];
    __syncthreads();
    float s = b[o];
    const float4* Wr = (const float4*)(W + (size_t)o * 128);
    for (int k4 = 0; k4 < 32; k4++) {
        float4 wv = Wr[k4];
        s += er[4*k4]   * wv.x + er[4*k4+1] * wv.y
           + er[4*k4+2] * wv.z + er[4*k4+3] * wv.w;
    }
    xtab[((size_t)(dir * 128 + sym)) * 512 + o] = f2bf(s);
}

// ---------------------------------------------------------------------------
// Merged weight transpose+convert (+K zero-padding) + misc init segment.
// ---------------------------------------------------------------------------
struct WtSeg { const float* W; u16* out; int Kd, Ks, Nw, tot; };
struct WtArgs {
    WtSeg seg[9];
    int* deg; float* bias5; const float* b0; const float* bip;
};
__global__ void k_wt_all(WtArgs a) {
    if (blockIdx.y == 9) {
        int gid = blockIdx.x * 256 + threadIdx.x;
        if (gid < N_) a.deg[gid] = 0;
        int b = gid - 10240;
        if (b >= 0 && b < 640) a.bias5[b] = (b < 512) ? a.b0[b] : a.bip[b - 512];
        return;
    }
    WtSeg sg = a.seg[blockIdx.y];
    int i = blockIdx.x * 256 + threadIdx.x;
    if (i >= sg.tot) return;
    int k = i % sg.Kd, n = (i / sg.Kd) % sg.Nw, s = i / (sg.Kd * sg.Nw);
    float v = (k < sg.Ks) ? sg.W[((size_t)s * sg.Ks + k) * sg.Nw + n] : 0.f;
    sg.out[i] = f2bf(v);
}

// ---------------------------------------------------------------------------
// Bi-LSTM: block = 512 threads (8 waves) x 16 sequences, one direction.
// Wave w owns hidden units [16w,16w+16) for all 4 gates (64 VGPR of Whh).
// h in LDS fragment-major, double-buffered; raw lgkmcnt-only barrier;
// xtab folded into MFMA C-init, prefetched one step ahead.
// Block-uniform NOMASK fast path. (R10's fused-reciprocal gate math and
// setprio REVERTED: fusion cut VALU issue but lengthened the serial trans
// chain -> +24us; setprio needs wave role-diversity, absent in lockstep.)
// ---------------------------------------------------------------------------
__global__ __launch_bounds__(512, 2) void k_lstm(
    const u16* __restrict__ xtab,      // [2][128][512] bf16 (bias folded)
    const int* __restrict__ syms,      // [N][32]
    const int* __restrict__ smask,     // [N][32]
    const float* __restrict__ WhhF,    // [512][128]
    const float* __restrict__ WhhB,
    u16* __restrict__ hcat)            // [N][256] bf16 (fwd | bwd)
{
    __shared__ u16 h_buf0[2048];       // [16 slabs][16 seq][8 elems]
    __shared__ u16 h_buf1[2048];
    __shared__ int sym_l[512];         // [t][seq]
    __shared__ int msk_l[512];         // [t][seq]
    __shared__ int anymask;

    int tid = threadIdx.x;
    int w = tid >> 6, l = tid & 63, l15 = l & 15, lg = l >> 4;
    int dir = blockIdx.y;
    int n0 = blockIdx.x * 16;
    const float* Whh = dir ? WhhB : WhhF;

    if (tid == 0) anymask = 0;
    int m0 = 0;
    for (int i = tid; i < 512; i += 512) {
        int seq = i >> 5, t = i & 31;
        int mv = smask[(size_t)n0 * 32 + i];
        sym_l[t * 16 + seq] = syms[(size_t)n0 * 32 + i];
        msk_l[t * 16 + seq] = mv;
        m0 |= (mv == 0);
    }
    for (int i = tid; i < 2048; i += 512) h_buf0[i] = 0;
    if (__ballot(m0) != 0ull && l == 0) anymask = 1;

    // A fragments: wave w covers gate gg, units 128*gg + 16*w + row
    short8 aw[4][4];
#pragma unroll
    for (int gg = 0; gg < 4; gg++)
#pragma unroll
    for (int kk = 0; kk < 4; kk++) {
        const float* p = Whh + (size_t)(128 * gg + 16 * w + l15) * 128 + 32 * kk + 8 * lg;
        const float4* pp = (const float4*)p;
        float4 x0 = pp[0], x1 = pp[1];
        short8 v;
        v[0] = (short)f2bf(x0.x); v[1] = (short)f2bf(x0.y);
        v[2] = (short)f2bf(x0.z); v[3] = (short)f2bf(x0.w);
        v[4] = (short)f2bf(x1.x); v[5] = (short)f2bf(x1.y);
        v[6] = (short)f2bf(x1.z); v[7] = (short)f2bf(x1.w);
        aw[gg][kk] = v;
    }

    float hreg[4] = {0, 0, 0, 0};
    float creg[4] = {0, 0, 0, 0};
    int jb = 16 * w + 4 * lg;          // hidden-unit base for this lane
    int wsk = 2 * w + (lg >> 1);       // write slab index (= jb>>3)
    int wof = (wsk * 16 + l15) * 8 + 4 * (lg & 1);
    const u16* xbase = xtab + (size_t)dir * 128 * 512 + jb;
    __syncthreads();
    bool masked = anymask != 0;

    u32x2 xt[4];
    {   // prologue: prefetch xtab gate inputs for step 0
        int t0 = dir ? 31 : 0;
        int sym0 = sym_l[t0 * 16 + l15];
        const u16* xr = xbase + (size_t)sym0 * 512;
#pragma unroll
        for (int gg = 0; gg < 4; gg++) xt[gg] = *(const u32x2*)(xr + gg * 128);
    }

    auto step = [&](int st, const u16* rb, u16* wb, bool wr, bool usemask) {
        int t = dir ? (31 - st) : st;

        // B fragments: contiguous 1KB slab per wave, conflict-free
        short8 bh[4];
#pragma unroll
        for (int kk = 0; kk < 4; kk++)
            bh[kk] = *(const short8*)&rb[((kk * 4 + lg) * 16 + l15) * 8];

        f32x4 acc[4];
#pragma unroll
        for (int gg = 0; gg < 4; gg++) {
            // init C with the xtab gate inputs (x@Wih.T + b)
            f32x4 a = { asf(xt[gg][0] << 16), asf(xt[gg][0] & 0xffff0000u),
                        asf(xt[gg][1] << 16), asf(xt[gg][1] & 0xffff0000u) };
#pragma unroll
            for (int kk = 0; kk < 4; kk++)
                a = __builtin_amdgcn_mfma_f32_16x16x32_bf16(aw[gg][kk], bh[kk], a, 0, 0, 0);
            acc[gg] = a;
        }

        // prefetch next step's xtab inputs into the SAME regs; the raw
        // barrier below does NOT drain vmcnt -> latency spans the barrier.
        if (wr) {
            int stn = st + 1;
            int tn = dir ? (31 - stn) : stn;
            int symn = sym_l[tn * 16 + l15];
            const u16* xr = xbase + (size_t)symn * 512;
#pragma unroll
            for (int gg = 0; gg < 4; gg++) xt[gg] = *(const u32x2*)(xr + gg * 128);
        }

        if (usemask) {
            int mt_i = msk_l[t * 16 + l15];
            bool mb = mt_i != 0;
#pragma unroll
            for (int r = 0; r < 4; r++) {
                float i_ = fsig(acc[0][r]), f_ = fsig(acc[1][r]);
                float g_ = ftanh_(acc[2][r]), o_ = fsig(acc[3][r]);
                float cn = f_ * creg[r] + i_ * g_;
                float hn = o_ * ftanh_(cn);
                hreg[r] = mb ? hn : hreg[r];
                creg[r] = mb ? cn : creg[r];
            }
        } else {
#pragma unroll
            for (int r = 0; r < 4; r++) {
                float i_ = fsig(acc[0][r]), f_ = fsig(acc[1][r]);
                float g_ = ftanh_(acc[2][r]), o_ = fsig(acc[3][r]);
                float cn = f_ * creg[r] + i_ * g_;
                hreg[r] = o_ * ftanh_(cn);
                creg[r] = cn;
            }
        }
        if (wr) {
            u32x2 pk;
            pk[0] = cvt_pk_bf16(hreg[0], hreg[1]);
            pk[1] = cvt_pk_bf16(hreg[2], hreg[3]);
            *(u32x2*)&wb[wof] = pk;
            // raw barrier: wait LDS ops only, NOT vmcnt
            asm volatile("s_waitcnt lgkmcnt(0)" ::: "memory");
            __builtin_amdgcn_s_barrier();
        }
    };

    if (masked) {
        for (int st2 = 0; st2 < 15; st2++) {
            step(2 * st2,     h_buf0, h_buf1, true, true);
            step(2 * st2 + 1, h_buf1, h_buf0, true, true);
        }
        step(30, h_buf0, h_buf1, true, true);
        step(31, h_buf1, h_buf0, false, true);
    } else {
        for (int st2 = 0; st2 < 15; st2++) {
            step(2 * st2,     h_buf0, h_buf1, true, false);
            step(2 * st2 + 1, h_buf1, h_buf0, true, false);
        }
        step(30, h_buf0, h_buf1, true, false);
        step(31, h_buf1, h_buf0, false, false);
    }

    // final hidden -> hcat[n][dir*128 + j]
    {
        u32x2 pk;
        pk[0] = cvt_pk_bf16(hreg[0], hreg[1]);
        pk[1] = cvt_pk_bf16(hreg[2], hreg[3]);
        *(u32x2*)&hcat[(size_t)(n0 + l15) * 256 + dir * 128 + jb] = pk;
    }
}

// ---------------------------------------------------------------------------
// Generic MFMA GEMM: C[M,128] = act(A1@B1 [+ A2@B2] + bias), bf16 in/out.
// ---------------------------------------------------------------------------
template<int ACT, int DUAL>
__global__ __launch_bounds__(256) void k_gemm(
    const u16* __restrict__ A1, int lda1, int soA1,
    const u16* __restrict__ A2, int lda2, int soA2,
    const u16* __restrict__ B1, int soB1,
    const u16* __restrict__ B2, int soB2,
    const float* __restrict__ bias, int soBias,
    u16* __restrict__ C, int ldc, int soC, int M, int K)
{
    int s = blockIdx.y;
    A1 += (size_t)s * soA1;
    if (DUAL) A2 += (size_t)s * soA2;
    B1 += (size_t)s * soB1;
    if (DUAL) B2 += (size_t)s * soB2;
    if (bias) bias += (size_t)s * soBias;
    C += (size_t)s * soC;

    int tid = threadIdx.x;
    int w = tid >> 6, l = tid & 63, l15 = l & 15, lg = l >> 4;
    int mbase = blockIdx.x * 64 + w * 16;
    int arow = mbase + l15; if (arow >= M) arow = M - 1;

    f32x4 acc[8];
#pragma unroll
    for (int nt = 0; nt < 8; nt++) {
        float bv = bias ? bias[16 * nt + l15] : 0.f;
        acc[nt] = (f32x4){bv, bv, bv, bv};
    }
    for (int k0 = 0; k0 < K; k0 += 32) {
        int k = k0 + 8 * lg;
        short8 a1 = *(const short8*)&A1[(size_t)arow * lda1 + k];
        short8 a2;
        if (DUAL) a2 = *(const short8*)&A2[(size_t)arow * lda2 + k];
#pragma unroll
        for (int nt = 0; nt < 8; nt++) {
            short8 b1 = *(const short8*)&B1[(size_t)(16 * nt + l15) * K + k];
            acc[nt] = __builtin_amdgcn_mfma_f32_16x16x32_bf16(a1, b1, acc[nt], 0, 0, 0);
            if (DUAL) {
                short8 b2 = *(const short8*)&B2[(size_t)(16 * nt + l15) * K + k];
                acc[nt] = __builtin_amdgcn_mfma_f32_16x16x32_bf16(a2, b2, acc[nt], 0, 0, 0);
            }
        }
    }
#pragma unroll
    for (int nt = 0; nt < 8; nt++)
#pragma unroll
    for (int r = 0; r < 4; r++) {
        int m = mbase + 4 * lg + r;
        if (m < M) {
            float v = acc[nt][r];
            if (ACT == 1) v = lrelu(v);
            C[(size_t)m * ldc + 16 * nt + l15] = f2bf(v);
        }
    }
}

// ---------------------------------------------------------------------------
// Fused: y==0 -> vec_url GEMM (F0 cols 0..127, pitch 640);
//        y==1 -> embedding/ip pack (F0 cols 128..543).
// F0 cols 544..639 are never written: they feed only the zero-padded K>=32
// weights of the ip stream (poison bf16 is a finite denormal -> inert).
// ---------------------------------------------------------------------------
__global__ __launch_bounds__(256) void k_fcpack(
    const u16* __restrict__ hcat, const u16* __restrict__ Bt,   // [128][256]
    const float* __restrict__ bias, u16* __restrict__ F0,
    const int* __restrict__ ic, const int* __restrict__ ico,
    const int* __restrict__ isl, const float* __restrict__ ip,
    const float* __restrict__ ecat, const float* __restrict__ ecou,
    const float* __restrict__ esl, int M)
{
    if (blockIdx.y == 1) {
        int gid = blockIdx.x * 256 + threadIdx.x;   // 157*256 = 40192 threads
        const int TOT = N_ * 416;
        for (int i = gid; i < TOT; i += 40192) {
            int n = i / 416, c = i - n * 416;
            float v;
            if (c < 128)      v = ecat[(size_t)ic[n]  * 128 + c];
            else if (c < 256) v = ecou[(size_t)ico[n] * 128 + (c - 128)];
            else if (c < 384) v = esl [(size_t)isl[n] * 128 + (c - 256)];
            else              v = ip  [(size_t)n * 32 + (c - 384)];
            F0[(size_t)n * 640 + 128 + c] = f2bf(v);
        }
        return;
    }
    int tid = threadIdx.x;
    int w = tid >> 6, l = tid & 63, l15 = l & 15, lg = l >> 4;
    int mbase = blockIdx.x * 64 + w * 16;
    int arow = mbase + l15; if (arow >= M) arow = M - 1;

    f32x4 acc[8];
#pragma unroll
    for (int nt = 0; nt < 8; nt++) {
        float bv = bias[16 * nt + l15];
        acc[nt] = (f32x4){bv, bv, bv, bv};
    }
    for (int k0 = 0; k0 < 256; k0 += 32) {
        int k = k0 + 8 * lg;
        short8 a1 = *(const short8*)&hcat[(size_t)arow * 256 + k];
#pragma unroll
        for (int nt = 0; nt < 8; nt++) {
            short8 b1 = *(const short8*)&Bt[(size_t)(16 * nt + l15) * 256 + k];
            acc[nt] = __builtin_amdgcn_mfma_f32_16x16x32_bf16(a1, b1, acc[nt], 0, 0, 0);
        }
    }
#pragma unroll
    for (int nt = 0; nt < 8; nt++)
#pragma unroll
    for (int r = 0; r < 4; r++) {
        int m = mbase + 4 * lg + r;
        if (m < M)
            F0[(size_t)m * 640 + 16 * nt + l15] = f2bf(lrelu(acc[nt][r]));
    }
}

// ---------------------------------------------------------------------------
// CSR build
// ---------------------------------------------------------------------------
__global__ void k_hist(const int* __restrict__ dst, int E, int* __restrict__ deg) {
    int e = blockIdx.x * 256 + threadIdx.x;
    if (e < E) atomicAdd(&deg[dst[e]], 1);
}
__global__ void k_scan(const int* __restrict__ deg, int* __restrict__ rowptr,
                       int* __restrict__ cursor, int n) {
    __shared__ int part[1024];
    int tid = threadIdx.x;
    const int CH = 10;
    int base = tid * CH;
    int s = 0;
#pragma unroll
    for (int i = 0; i < CH; i++) { int idx = base + i; if (idx < n) s += deg[idx]; }
    part[tid] = s; __syncthreads();
    for (int off = 1; off < 1024; off <<= 1) {
        int v = (tid >= off) ? part[tid - off] : 0;
        __syncthreads();
        part[tid] += v;
        __syncthreads();
    }
    int run = part[tid] - s;
    for (int i = 0; i < CH; i++) {
        int idx = base + i;
        if (idx < n) { rowptr[idx] = run; cursor[idx] = run; run += deg[idx]; }
    }
    if (tid == 1023) rowptr[n] = part[1023];
}
__global__ void k_fill(const int* __restrict__ src, const int* __restrict__ dst, int E,
                       int* __restrict__ cursor, int* __restrict__ colsrc) {
    int e = blockIdx.x * 256 + threadIdx.x;
    if (e < E) {
        int pos = atomicAdd(&cursor[dst[e]], 1);
        colsrc[pos] = src[e];
    }
}

// ---------------------------------------------------------------------------
// Mean aggregation: column-chunked. Row pitch 640 u16 = 320 u32 = 5 chunks
// of 64 u32. Grid (N/4, 5); per-chunk table 2.56 MB < 4 MB L2/XCD.
// ---------------------------------------------------------------------------
__global__ __launch_bounds__(256) void k_agg(const u16* __restrict__ F,
                                             const int* __restrict__ rowptr,
                                             const int* __restrict__ colsrc,
                                             u16* __restrict__ out, int N) {
    int w = threadIdx.x >> 6, l = threadIdx.x & 63;
    int n = blockIdx.x * 4 + w;
    if (n >= N) return;
    int cu = blockIdx.y * 64 + l;          // u32 column in [0,320)
    const u32* Fc = (const u32*)F;         // row pitch 320 u32
    int beg = rowptr[n], end = rowptr[n + 1];
    float a0 = 0.f, a1 = 0.f;

    int e = beg;
    for (; e + 8 <= end; e += 8) {
        int s[8];
#pragma unroll
        for (int j = 0; j < 8; j++) s[j] = colsrc[e + j];
        u32 v[8];
#pragma unroll
        for (int j = 0; j < 8; j++) v[j] = Fc[(size_t)s[j] * 320 + cu];
#pragma unroll
        for (int j = 0; j < 8; j++) {
            a0 += asf(v[j] << 16);
            a1 += asf(v[j] & 0xffff0000u);
        }
    }
    for (; e < end; e++) {
        u32 v = Fc[(size_t)colsrc[e] * 320 + cu];
        a0 += asf(v << 16);
        a1 += asf(v & 0xffff0000u);
    }

    int dg = end - beg; if (dg < 1) dg = 1;
    float inv = 1.f / (float)dg;
    ((u32*)out)[(size_t)n * 320 + cu] = cvt_pk_bf16(a0 * inv, a1 * inv);
}

// ---------------------------------------------------------------------------
// Fused attnlin-GEMM + attention: block = 5 waves = 80 rows = 16 nodes.
// ---------------------------------------------------------------------------
__global__ __launch_bounds__(320) void k_zattn(
    const u16* __restrict__ H1,        // rows r=(n*5+s) at H1 + r*128
    const u16* __restrict__ Bt,        // wt_attn [128][128]
    const float* __restrict__ attnW,   // [128]
    float* __restrict__ aOut,          // [N][5]
    u16* __restrict__ hT)              // [N][128]
{
    constexpr int ZP = 136;            // u16 pitch (272 B, 16B-aligned rows)
    __shared__ u16 zl[80 * ZP];
    int tid = threadIdx.x;
    int w = tid >> 6, l = tid & 63, l15 = l & 15, lg = l >> 4;
    int rbase = blockIdx.x * 80 + w * 16;

    f32x4 acc[8];
#pragma unroll
    for (int nt = 0; nt < 8; nt++) acc[nt] = (f32x4){0.f, 0.f, 0.f, 0.f};
    for (int k0 = 0; k0 < 128; k0 += 32) {
        int k = k0 + 8 * lg;
        short8 a1 = *(const short8*)&H1[(size_t)(rbase + l15) * 128 + k];
#pragma unroll
        for (int nt = 0; nt < 8; nt++) {
            short8 b1 = *(const short8*)&Bt[(size_t)(16 * nt + l15) * 128 + k];
            acc[nt] = __builtin_amdgcn_mfma_f32_16x16x32_bf16(a1, b1, acc[nt], 0, 0, 0);
        }
    }
#pragma unroll
    for (int nt = 0; nt < 8; nt++)
#pragma unroll
    for (int r = 0; r < 4; r++)
        zl[(w * 16 + 4 * lg + r) * ZP + 16 * nt + l15] = f2bf(acc[nt][r]);
    __syncthreads();

    if (tid < 256) {
        int node = tid >> 4;           // 0..15
        int j = tid & 15;
        int d0 = j * 8;
        float4 wa0 = *(const float4*)(attnW + d0);
        float4 wa1 = *(const float4*)(attnW + d0 + 4);
        float z[5][8], lgt[5];
#pragma unroll
        for (int s = 0; s < 5; s++) {
            const u16* zr = &zl[(node * 5 + s) * ZP + d0];
            u32x4 v = *(const u32x4*)zr;
#pragma unroll
            for (int q = 0; q < 4; q++) {
                z[s][2*q]   = asf(v[q] << 16);
                z[s][2*q+1] = asf(v[q] & 0xffff0000u);
            }
            float p = z[s][0]*wa0.x + z[s][1]*wa0.y + z[s][2]*wa0.z + z[s][3]*wa0.w
                    + z[s][4]*wa1.x + z[s][5]*wa1.y + z[s][6]*wa1.z + z[s][7]*wa1.w;
#pragma unroll
            for (int m = 1; m < 16; m <<= 1) p += __shfl_xor(p, m, 64);
            lgt[s] = p;
        }
        float mx = lgt[0];
#pragma unroll
        for (int s = 1; s < 5; s++) mx = fmaxf(mx, lgt[s]);
        float ex[5], sum = 0.f;
#pragma unroll
        for (int s = 0; s < 5; s++) { ex[s] = __expf(lgt[s] - mx); sum += ex[s]; }
        float inv = 1.f / sum;
        float a[5];
#pragma unroll
        for (int s = 0; s < 5; s++) a[s] = ex[s] * inv;
        float h[8] = {0,0,0,0,0,0,0,0};
#pragma unroll
        for (int s = 0; s < 5; s++)
#pragma unroll
            for (int q = 0; q < 8; q++) h[q] += a[s] * z[s][q];
        int gn = blockIdx.x * 16 + node;
        u32x4 o;
#pragma unroll
        for (int q = 0; q < 4; q++) o[q] = cvt_pk_bf16(h[2*q], h[2*q+1]);
        *(u32x4*)&hT[(size_t)gn * 128 + d0] = o;
        if (j == 0) {
#pragma unroll
            for (int s = 0; s < 5; s++) aOut[(size_t)gn * 5 + s] = a[s];
        }
    }
}

// ---------------------------------------------------------------------------
// Edge MLP fused: score + attn_e outputs.
// ---------------------------------------------------------------------------
__global__ __launch_bounds__(256) void k_edge(const u16* __restrict__ hT,
                                              const int* __restrict__ esrc,
                                              const int* __restrict__ edst,
                                              const u16* __restrict__ fcWt,  // [128][256]
                                              const float* __restrict__ fcb,
                                              const float* __restrict__ fcoW, // [128][2]
                                              const float* __restrict__ fcob,
                                              const float* __restrict__ aA,   // [N][5]
                                              float* __restrict__ score,      // [E2][2]
                                              float* __restrict__ attne,      // [E2][2][5]
                                              int E2) {
    int tid = threadIdx.x;
    int w = tid >> 6, l = tid & 63, l15 = l & 15, lg = l >> 4;
    int eb = (blockIdx.x * 4 + w) * 16;
    int arow = eb + l15; if (arow >= E2) arow = E2 - 1;
    int sn = esrc[arow], dn = edst[arow];

    f32x4 acc[8];
#pragma unroll
    for (int nt = 0; nt < 8; nt++) {
        float bv = fcb[16 * nt + l15];
        acc[nt] = (f32x4){bv, bv, bv, bv};
    }
#pragma unroll
    for (int kk = 0; kk < 8; kk++) {
        int k = 32 * kk + 8 * lg;
        const u16* ap = (k < 128) ? &hT[(size_t)sn * 128 + k]
                                  : &hT[(size_t)dn * 128 + (k - 128)];
        short8 a = *(const short8*)ap;
#pragma unroll
        for (int nt = 0; nt < 8; nt++) {
            short8 b = *(const short8*)&fcWt[(size_t)(16 * nt + l15) * 256 + k];
            acc[nt] = __builtin_amdgcn_mfma_f32_16x16x32_bf16(a, b, acc[nt], 0, 0, 0);
        }
    }
    float p0[4] = {0,0,0,0}, p1[4] = {0,0,0,0};
#pragma unroll
    for (int nt = 0; nt < 8; nt++) {
        int c = 16 * nt + l15;
        float w0 = fcoW[c * 2], w1 = fcoW[c * 2 + 1];
#pragma unroll
        for (int r = 0; r < 4; r++) {
            float hd = lrelu(acc[nt][r]);
            p0[r] += hd * w0; p1[r] += hd * w1;
        }
    }
#pragma unroll
    for (int m = 1; m < 16; m <<= 1) {
#pragma unroll
        for (int r = 0; r < 4; r++) {
            p0[r] += __shfl_xor(p0[r], m, 64);
            p1[r] += __shfl_xor(p1[r], m, 64);
        }
    }
    if (l15 == 0) {
        float b0v = fcob[0], b1v = fcob[1];
#pragma unroll
        for (int r = 0; r < 4; r++) {
            int e = eb + 4 * lg + r;
            if (e < E2) {
                score[(size_t)e * 2 + 0] = p0[r] + b0v;
                score[(size_t)e * 2 + 1] = p1[r] + b1v;
            }
        }
    }
    // fused attn_e: wave covers 16 edges x 10 floats, coalesced writes
#pragma unroll
    for (int pass = 0; pass < 3; pass++) {
        int idx = pass * 64 + l;
        if (idx < 160) {
            int e = eb + idx / 10;
            int j = idx % 10;
            int s = esrc[e];
            attne[(size_t)e * 10 + j] = aA[(size_t)s * 5 + (j >= 5 ? j - 5 : j)];
        }
    }
}

// ---------------------------------------------------------------------------
extern "C" void kernel_launch(void* const* d_in, const int* in_sizes, int n_in,
                              void* d_out, int out_size, void* d_ws, size_t ws_size,
                              hipStream_t stream) {
    const int* inp_s   = (const int*)d_in[0];
    const int* inp_sm  = (const int*)d_in[1];
    const int* inp_c   = (const int*)d_in[2];
    const int* inp_co  = (const int*)d_in[3];
    const int* inp_sl  = (const int*)d_in[4];
    const float* inp_ip = (const float*)d_in[5];
    const int* blk_src = (const int*)d_in[6];
    const int* blk_dst = (const int*)d_in[7];
    const int* e_src   = (const int*)d_in[8];
    const int* e_dst   = (const int*)d_in[9];
    const float* emb_url = (const float*)d_in[10];
    const float* emb_cat = (const float*)d_in[11];
    const float* emb_cou = (const float*)d_in[12];
    const float* emb_sl  = (const float*)d_in[13];
    const float* Wih_f = (const float*)d_in[14];
    const float* Whh_f = (const float*)d_in[15];
    const float* b_f   = (const float*)d_in[16];
    const float* Wih_b = (const float*)d_in[17];
    const float* Whh_b = (const float*)d_in[18];
    const float* b_b   = (const float*)d_in[19];
    const float* fc_lstm_W = (const float*)d_in[20];
    const float* fc_lstm_b = (const float*)d_in[21];
    const float* attnlin_W = (const float*)d_in[22];
    const float* attn_W    = (const float*)d_in[23];
    /* d_in[24] attn_b: softmax shift-invariant, unused */
    const float* W0_self  = (const float*)d_in[25];
    const float* W0_neigh = (const float*)d_in[26];
    const float* b0       = (const float*)d_in[27];
    const float* Wip_self  = (const float*)d_in[28];
    const float* Wip_neigh = (const float*)d_in[29];
    const float* bip       = (const float*)d_in[30];
    const float* W1_self  = (const float*)d_in[31];
    const float* W1_neigh = (const float*)d_in[32];
    const float* b1       = (const float*)d_in[33];
    const float* fc_W  = (const float*)d_in[34];
    const float* fc_b  = (const float*)d_in[35];
    const float* fco_W = (const float*)d_in[36];
    const float* fco_b = (const float*)d_in[37];

    char* ws = (char*)d_ws;
    size_t off = 0;
    auto alloc = [&](size_t bytes) -> char* {
        char* p = ws + off;
        off += (bytes + 255) & ~(size_t)255;
        return p;
    };
    u16* xtab      = (u16*)alloc((size_t)2 * 128 * 512 * 2);
    u16* hcat      = (u16*)alloc((size_t)N_ * 256 * 2);
    u16* wt_fclstm = (u16*)alloc((size_t)128 * 256 * 2);
    u16* wt_w05s   = (u16*)alloc((size_t)5 * 128 * 128 * 2);  // 4 emb + padded ip
    u16* wt_w05n   = (u16*)alloc((size_t)5 * 128 * 128 * 2);
    u16* wt_w1s    = (u16*)alloc((size_t)5 * 128 * 128 * 2);
    u16* wt_w1n    = (u16*)alloc((size_t)5 * 128 * 128 * 2);
    u16* wt_attn   = (u16*)alloc((size_t)128 * 128 * 2);
    u16* wt_fc     = (u16*)alloc((size_t)128 * 256 * 2);
    float* bias5   = (float*)alloc((size_t)5 * 128 * 4);
    u16* F0        = (u16*)alloc((size_t)N_ * 640 * 2);       // pitch 640 (chunked agg)
    u16* NEI       = (u16*)alloc((size_t)N_ * 640 * 2);
    u16* F1        = (u16*)alloc((size_t)N_ * 640 * 2);
    u16* H1        = (u16*)alloc((size_t)N_ * 640 * 2);
    u16* hT        = (u16*)alloc((size_t)N_ * 128 * 2);
    float* aA      = (float*)alloc((size_t)N_ * 5 * 4);
    int* deg       = (int*)alloc((size_t)N_ * 4);
    int* rowptr    = (int*)alloc((size_t)(N_ + 1) * 4);
    int* cursor    = (int*)alloc((size_t)N_ * 4);
    int* colsrc    = (int*)alloc((size_t)E_ * 4);
    (void)ws_size; (void)in_sizes; (void)n_in; (void)out_size;

    float* out_score = (float*)d_out;
    float* out_attne = out_score + (size_t)2 * E2_;

    // --- LSTM prep + weight prep (+deg zero, bias5 build) ---
    k_xtab<<<dim3(128, 2), dim3(512), 0, stream>>>(emb_url, Wih_f, b_f, Wih_b, b_b, xtab);
    {
        WtArgs a;
        a.seg[0] = {fc_lstm_W, wt_fclstm,            256, 256, 128, 1 * 128 * 256};
        a.seg[1] = {W0_self,   wt_w05s,              128, 128, 128, 4 * 128 * 128};
        a.seg[2] = {W0_neigh,  wt_w05n,              128, 128, 128, 4 * 128 * 128};
        a.seg[3] = {Wip_self,  wt_w05s + 4 * 16384,  128,  32, 128, 1 * 128 * 128};
        a.seg[4] = {Wip_neigh, wt_w05n + 4 * 16384,  128,  32, 128, 1 * 128 * 128};
        a.seg[5] = {W1_self,   wt_w1s,               128, 128, 128, 5 * 128 * 128};
        a.seg[6] = {W1_neigh,  wt_w1n,               128, 128, 128, 5 * 128 * 128};
        a.seg[7] = {attnlin_W, wt_attn,              128, 128, 128, 1 * 128 * 128};
        a.seg[8] = {fc_W,      wt_fc,                256, 256, 128, 1 * 128 * 256};
        a.deg = deg; a.bias5 = bias5; a.b0 = b0; a.bip = bip;
        k_wt_all<<<dim3((5 * 128 * 128 + 255) / 256, 10), dim3(256), 0, stream>>>(a);
    }

    // --- CSR build ---
    k_hist<<<dim3((E_ + 255) / 256), dim3(256), 0, stream>>>(blk_dst, E_, deg);
    k_scan<<<dim3(1), dim3(1024), 0, stream>>>(deg, rowptr, cursor, N_);
    k_fill<<<dim3((E_ + 255) / 256), dim3(256), 0, stream>>>(blk_src, blk_dst, E_, cursor, colsrc);

    k_lstm<<<dim3(N_ / 16, 2), dim3(512), 0, stream>>>(xtab, inp_s, inp_sm, Whh_f, Whh_b, hcat);

    // vec_url GEMM + feature pack in one dispatch (F0 pitch 640)
    k_fcpack<<<dim3((N_ + 63) / 64, 2), dim3(256), 0, stream>>>(
        hcat, wt_fclstm, fc_lstm_b, F0,
        inp_c, inp_co, inp_sl, inp_ip, emb_cat, emb_cou, emb_sl, N_);

    // --- SAGE layer 0: chunked agg + 5-stream dual GEMM ---
    k_agg<<<dim3((N_ + 3) / 4, 5), dim3(256), 0, stream>>>(F0, rowptr, colsrc, NEI, N_);
    k_gemm<1, 1><<<dim3((N_ + 63) / 64, 5), dim3(256), 0, stream>>>(
        F0, 640, 128, NEI, 640, 128, wt_w05s, 128 * 128, wt_w05n, 128 * 128,
        bias5, 128, F1, 640, 128, N_, 128);

    // --- SAGE layer 1 ---
    k_agg<<<dim3((N_ + 3) / 4, 5), dim3(256), 0, stream>>>(F1, rowptr, colsrc, NEI, N_);
    k_gemm<1, 1><<<dim3((N_ + 63) / 64, 5), dim3(256), 0, stream>>>(
        F1, 640, 128, NEI, 640, 128, wt_w1s, 128 * 128, wt_w1n, 128 * 128,
        b1, 128, H1, 640, 128, N_, 128);

    // --- fused attention (GEMM + softmax + fuse) ---
    k_zattn<<<dim3(N_ / 16), dim3(320), 0, stream>>>(H1, wt_attn, attn_W, aA, hT);

    // --- edge scoring (attn_e fused in) ---
    k_edge<<<dim3(E2_ / 64), dim3(256), 0, stream>>>(hT, e_src, e_dst, wt_fc, fc_b,
                                                     fco_W, fco_b, aA,
                                                     out_score, out_attne, E2_);
}